// Round 7
// baseline (173.525 us; speedup 1.0000x reference)
//
#include <hip/hip_runtime.h>

// RoiPooling: crop + bilinear 7x7 resize, TF1 resize_bilinear (align_corners=False).
// feat: (128,128,1024) fp32, rois: (512,4) fp32 [ymin,xmin,ymax,xmax], out: (512,7,7,1024) fp32.
//
// R9 = R8 with compile fix: use native ext_vector_type(4) floats uniformly
// (was mixing HIP_vector_type float4 with vfloat4 -> no conversion).
//
// R8 rationale: read-traffic cut (R4), request cut (R5), spatial order (R6/7)
// all ~neutral -> not traffic/locality bound. Only loads-in-flight has shown
// sensitivity. Old structure was bursty (per-block: roi-load -> 8 taps ->
// drain -> exit). New: block = (ROI, py) row, 256 threads, 7 cells, depth-2
// software pipeline (issue cell n+1 taps before blending cell n):
//  - ROI-param chain amortized 7x; no per-cell drain-to-exit;
//  - each wave holds 4-8KB of reads outstanding continuously;
//  - 3584 blocks (vs 25088): less launch churn;
//  - adjacent cells' shared tap columns hit L1 naturally.
// Keeps: dead-tap skipping (bit-exact), nt stores, XCD swizzle.

#define POOL_P 7
#define FEAT_C 1024
#define FEAT_W 128
#define GROUP_BLOCKS (8 * POOL_P)   // 56: 8 ROIs x 7 rows

typedef float vfloat4 __attribute__((ext_vector_type(4)));

// Issue the (up to) 4 tap loads for cell px into register set (TL,TR,BL,BR).
// Block-uniform conditions; skipped taps are never read before substitution.
#define LOADC(px, TL, TR, BL, BR)                                            \
    {                                                                        \
        const int cL = X0[px];                                               \
        const int cR = X1[px];                                               \
        const bool nx = NX[px];                                              \
        TL = row0[(size_t)(xmin + cL) * 256 + t];                            \
        if (nx)       TR = row0[(size_t)(xmin + cR) * 256 + t];              \
        if (ny)       BL = row1[(size_t)(xmin + cL) * 256 + t];              \
        if (nx && ny) BR = row1[(size_t)(xmin + cR) * 256 + t];              \
    }

// Blend cell px from register set and nt-store. Bit-exact substitutions:
//  !nx: fx==0 (weight exactly 0) or x1==x0 (tr IS tl)  -> tr:=tl.
//  !ny: fy==0 or y1==y0 -> bl:=tl; br:=tr makes bot==top exactly -> res=top.
//  nx&&!ny: br:=tr; !nx: br:=bl -> bot==bl exactly.
#define BLENDC(px, TL, TR, BL, BR)                                           \
    {                                                                        \
        vfloat4 tl = TL, tr = TR, bl = BL, br = BR;                          \
        const bool nx = NX[px];                                              \
        if (!nx) { tr = tl; }                                                \
        if (!ny) { bl = tl; }                                                \
        if (!(nx && ny)) { br = (!nx) ? bl : tr; }                           \
        const float fxv = FXa[px];                                           \
        vfloat4 res; float top, bot;                                         \
        top = tl.x + (tr.x - tl.x) * fxv; bot = bl.x + (br.x - bl.x) * fxv; res.x = top + (bot - top) * fy; \
        top = tl.y + (tr.y - tl.y) * fxv; bot = bl.y + (br.y - bl.y) * fxv; res.y = top + (bot - top) * fy; \
        top = tl.z + (tr.z - tl.z) * fxv; bot = bl.z + (br.z - bl.z) * fxv; res.z = top + (bot - top) * fy; \
        top = tl.w + (tr.w - tl.w) * fxv; bot = bl.w + (br.w - bl.w) * fxv; res.w = top + (bot - top) * fy; \
        __builtin_nontemporal_store(res, &op[(size_t)(px) * 256 + t]);       \
    }

__global__ __launch_bounds__(256) void roi_pool_kernel(
    const float* __restrict__ feat,
    const float* __restrict__ rois,
    float* __restrict__ out)
{
    // ---- XCD swizzle: blockIdx%8 fixed per ROI (group of 8 ROIs x 7 rows)
    const int i  = blockIdx.x;
    const int q  = i / GROUP_BLOCKS;
    const int k  = i - q * GROUP_BLOCKS;
    const int r  = 8 * q + (k & 7);           // ROI id
    const int py = k >> 3;                    // [0,7)

    // ---- ROI box (block-uniform)
    const vfloat4 roi = ((const vfloat4*)rois)[r];
    const int ymin = (int)roi.x;
    const int xmin = (int)roi.y;
    const int ymax = (int)roi.z;
    const int xmax = (int)roi.w;

    const float h = (float)(ymax - ymin + 1);
    const float w = (float)(xmax - xmin + 1);

    // exact reference rounding: src = p * (dim / 7.0f)
    const float src_y = (float)py * (h / 7.0f);
    const int y0 = (int)floorf(src_y);
    const int y1 = min(y0 + 1, ymax - ymin);
    const float fy = src_y - (float)y0;
    const bool ny = (y1 != y0) && (fy != 0.0f);

    const vfloat4* __restrict__ row0 = (const vfloat4*)(feat + (size_t)((ymin + y0) * FEAT_W) * FEAT_C);
    const vfloat4* __restrict__ row1 = (const vfloat4*)(feat + (size_t)((ymin + y1) * FEAT_W) * FEAT_C);

    // ---- column schedule (block-uniform; fully unrolled -> no scratch)
    int X0[POOL_P], X1[POOL_P];
    float FXa[POOL_P];
    bool NX[POOL_P];
    const float wstep = w / 7.0f;
    #pragma unroll
    for (int px = 0; px < POOL_P; ++px) {
        const float sx = (float)px * wstep;
        const int x0 = (int)floorf(sx);
        X0[px]  = x0;
        X1[px]  = min(x0 + 1, xmax - xmin);
        FXa[px] = sx - (float)x0;
        NX[px]  = (X1[px] != x0) && (FXa[px] != 0.0f);
    }

    const int t = threadIdx.x;                // float4 channel slice [0,256)
    vfloat4* __restrict__ op = (vfloat4*)(out + ((size_t)r * 49 + (size_t)py * 7) * FEAT_C);

    // ---- depth-2 software pipeline over the 7 cells (A/B register sets).
    // LOADC(n+1) is issued before BLENDC(n): each wave keeps the next cell's
    // taps in flight while blending the current one -> no vmcnt(0) drain
    // between cells, sustained outstanding reads across the whole row.
    vfloat4 Atl, Atr, Abl, Abr, Btl, Btr, Bbl, Bbr;
    LOADC(0, Atl, Atr, Abl, Abr);
    LOADC(1, Btl, Btr, Bbl, Bbr);
    BLENDC(0, Atl, Atr, Abl, Abr);
    LOADC(2, Atl, Atr, Abl, Abr);
    BLENDC(1, Btl, Btr, Bbl, Bbr);
    LOADC(3, Btl, Btr, Bbl, Bbr);
    BLENDC(2, Atl, Atr, Abl, Abr);
    LOADC(4, Atl, Atr, Abl, Abr);
    BLENDC(3, Btl, Btr, Bbl, Bbr);
    LOADC(5, Btl, Btr, Bbl, Bbr);
    BLENDC(4, Atl, Atr, Abl, Abr);
    LOADC(6, Atl, Atr, Abl, Abr);
    BLENDC(5, Btl, Btr, Bbl, Bbr);
    BLENDC(6, Atl, Atr, Abl, Abr);
}

extern "C" void kernel_launch(void* const* d_in, const int* in_sizes, int n_in,
                              void* d_out, int out_size, void* d_ws, size_t ws_size,
                              hipStream_t stream) {
    const float* feat = (const float*)d_in[0];   // (1,128,128,1024) fp32
    const float* rois = (const float*)d_in[1];   // (512,4) fp32
    float* out        = (float*)d_out;           // (512, 7*7*1024) fp32

    const int n_rois   = in_sizes[1] / 4;        // 512
    const int n_blocks = n_rois * POOL_P;        // 3584

    roi_pool_kernel<<<n_blocks, 256, 0, stream>>>(feat, rois, out);
}